// Round 2
// baseline (281.620 us; speedup 1.0000x reference)
//
#include <hip/hip_runtime.h>
#include <hip/hip_bf16.h>
#include <math.h>

#define BATCH 256
#define SEQ   512
#define DIM   128
#define LDSK  136   // padded LDS row stride in bf16 elems (272 B)
#define LDSF  132   // padded f32 relayout stride (528 B)

typedef __attribute__((ext_vector_type(8))) __bf16  bf16x8;
typedef __attribute__((ext_vector_type(4))) __bf16  bf16x4;
typedef __attribute__((ext_vector_type(4))) float   f32x4;

// ---------------- MFMA layer: acc[RT][8] = X(256xK) @ W^T + bias
// bw processed in chunks of 4 to keep peak live regs ~16 (was 32) -> no spill at 128-reg cap
template<int RT>
__device__ __forceinline__ void matmul_layer(
    const __bf16* __restrict__ Xa, const __bf16* __restrict__ wg,
    const float* __restrict__ bias, f32x4 (&acc)[RT][8], int wave, int m, int q)
{
  const int rowbase = wave * RT * 16;
#pragma unroll
  for (int ct = 0; ct < 8; ++ct) {
    const float b = bias[ct * 16 + m];
    const f32x4 bv = {b, b, b, b};
#pragma unroll
    for (int rt = 0; rt < RT; ++rt) acc[rt][ct] = bv;
  }
#pragma unroll
  for (int ks = 0; ks < 4; ++ks) {
    const int k0 = ks * 32 + q * 8;
    bf16x8 a[RT];
#pragma unroll
    for (int rt = 0; rt < RT; ++rt)
      a[rt] = *(const bf16x8*)(Xa + (rowbase + rt * 16 + m) * LDSK + k0);
#pragma unroll
    for (int cg = 0; cg < 2; ++cg) {
      bf16x8 bw[4];
#pragma unroll
      for (int cj = 0; cj < 4; ++cj)
        bw[cj] = *(const bf16x8*)(wg + ((cg * 4 + cj) * 16 + m) * DIM + k0);
#pragma unroll
      for (int rt = 0; rt < RT; ++rt)
#pragma unroll
        for (int cj = 0; cj < 4; ++cj)
          acc[rt][cg * 4 + cj] =
              __builtin_amdgcn_mfma_f32_16x16x32_bf16(a[rt], bw[cj], acc[rt][cg * 4 + cj], 0, 0, 0);
    }
  }
}

template<int RT>
__device__ __forceinline__ void stats_accum(
    const f32x4 (&acc)[RT][8], float* sumL, float* sqL, int m, int q)
{
#pragma unroll
  for (int ct = 0; ct < 8; ++ct) {
    float s = 0.f, ss = 0.f;
#pragma unroll
    for (int rt = 0; rt < RT; ++rt)
#pragma unroll
      for (int r = 0; r < 4; ++r) { const float v = acc[rt][ct][r]; s += v; ss += v * v; }
    s  += __shfl_xor(s, 16, 64);  s  += __shfl_xor(s, 32, 64);
    ss += __shfl_xor(ss, 16, 64); ss += __shfl_xor(ss, 32, 64);
    if (q == 0) { atomicAdd(&sumL[ct * 16 + m], s); atomicAdd(&sqL[ct * 16 + m], ss); }
  }
}

// fused BN-coef computation (redundant per thread, saves a barrier) + ReLU + store.
// Xa stripe is wave-private: rows [wave*RT*16, +RT*16) are written and re-read only by
// this wave, so NO __syncthreads is needed between this store and the next matmul.
template<int RT>
__device__ __forceinline__ void bn_relu_store(
    const f32x4 (&acc)[RT][8], __bf16* Xa, const float* sumL, const float* sqL,
    const float* __restrict__ g, const float* __restrict__ be,
    int wave, int m, int q)
{
  const int rowbase = wave * RT * 16;
#pragma unroll
  for (int ct = 0; ct < 8; ++ct) {
    const int n = ct * 16 + m;
    const float mean = sumL[n] * (1.0f / BATCH);
    const float var  = sqL[n]  * (1.0f / BATCH) - mean * mean;
    const float a = g[n] * rsqrtf(var + 1e-5f);
    const float c = be[n] - a * mean;
#pragma unroll
    for (int rt = 0; rt < RT; ++rt)
#pragma unroll
      for (int r = 0; r < 4; ++r) {
        const float y = fmaxf(0.f, a * acc[rt][ct][r] + c);
        const int row = rowbase + rt * 16 + q * 4 + r;
        Xa[row * LDSK + n] = (__bf16)y;
      }
  }
}

// ---------------- fused MLP kernel: one workgroup = one 256x128 batch problem
template<int NW, bool GATE>
__global__ __launch_bounds__(NW * 64, (NW == 8) ? 4 : 2)
void mlp_kernel(const float* __restrict__ xin, long xrow_stride,
                const __bf16* __restrict__ w1, const __bf16* __restrict__ w2,
                const __bf16* __restrict__ w3,
                const float* __restrict__ b1, const float* __restrict__ g1, const float* __restrict__ be1,
                const float* __restrict__ b2, const float* __restrict__ g2, const float* __restrict__ be2,
                const float* __restrict__ b3,
                const float* __restrict__ gate,   // c_out [256*128] when GATE
                float* __restrict__ out)          // GATE: s_out base; else c_out (ws)
{
  const int tid  = threadIdx.x;
  constexpr int NT = NW * 64;
  constexpr int RT = 16 / NW;       // row-tiles (of 16) per wave; 256 rows total
  const int wave = tid >> 6, lane = tid & 63;
  const int m = lane & 15, q = lane >> 4;
  const int slice = GATE ? blockIdx.x : 0;
  const float* x0 = GATE ? (xin + (long)slice * DIM) : xin;

  __shared__ __align__(16) char XaRaw[BATCH * LDSK * 2];   // 69632 B; reused as f32 relayout buf
  __bf16* Xa = (__bf16*)XaRaw;
  __shared__ float sum1[DIM], sq1[DIM], sum2[DIM], sq2[DIM];

  for (int t = tid; t < DIM; t += NT) { sum1[t] = 0.f; sq1[t] = 0.f; sum2[t] = 0.f; sq2[t] = 0.f; }

  // stage X -> LDS bf16 (coalesced: 32 lanes span one 512B row); unroll 4 caps in-flight regs
  {
    const int rpi = NT / 32;
    const int r0  = tid >> 5;
    const int c4  = (tid & 31) * 4;
#pragma unroll 4
    for (int it = 0; it < BATCH / rpi; ++it) {
      const int r = it * rpi + r0;
      const float4 v = *(const float4*)(x0 + (long)r * xrow_stride + c4);
      bf16x4 h = { (__bf16)v.x, (__bf16)v.y, (__bf16)v.z, (__bf16)v.w };
      *(bf16x4*)(Xa + r * LDSK + c4) = h;
    }
  }
  __syncthreads();

  f32x4 acc[RT][8];

  // Layer 1: matmul -> stats -> barrier -> fused coefs+ReLU+store (wave-private, no 2nd barrier)
  matmul_layer<RT>(Xa, w1, b1, acc, wave, m, q);
  stats_accum<RT>(acc, sum1, sq1, m, q);
  __syncthreads();
  bn_relu_store<RT>(acc, Xa, sum1, sq1, g1, be1, wave, m, q);

  // Layer 2
  matmul_layer<RT>(Xa, w2, b2, acc, wave, m, q);
  stats_accum<RT>(acc, sum2, sq2, m, q);
  __syncthreads();
  bn_relu_store<RT>(acc, Xa, sum2, sq2, g2, be2, wave, m, q);

  // Layer 3 + epilogue
  matmul_layer<RT>(Xa, w3, b3, acc, wave, m, q);

  if constexpr (GATE) {
    // Xa dead; reuse as f32 relayout buffer (128 rows x LDSF) so gate loads and global
    // stores are float4 with full 512B segments. (shapes assume NW=8 / RT=2)
    float* Xf = (float*)XaRaw;
    const int c4 = (tid & 31) * 4;
    const int r0 = tid >> 5;
    __syncthreads();                     // all waves done reading Xa
#pragma unroll
    for (int rt = 0; rt < RT; ++rt) {
#pragma unroll
      for (int ct = 0; ct < 8; ++ct)
#pragma unroll
        for (int r = 0; r < 4; ++r)
          Xf[(wave * 16 + q * 4 + r) * LDSF + ct * 16 + m] = acc[rt][ct][r];
      __syncthreads();
#pragma unroll 4
      for (int it = 0; it < 8; ++it) {
        const int crow = it * 16 + r0;                          // 0..127
        const int grow = (crow >> 4) * 32 + rt * 16 + (crow & 15);
        float4 y = *(const float4*)(Xf + crow * LDSF + c4);
        const float4 gv = *(const float4*)(gate + grow * DIM + c4);
        y.x *= gv.x; y.y *= gv.y; y.z *= gv.z; y.w *= gv.w;
        *(float4*)(out + ((long)grow * SEQ + slice) * DIM + c4) = y;
      }
      if (rt + 1 < RT) __syncthreads();  // before overwriting Xf with next chunk
    }
  } else {
    const int rowbase = wave * RT * 16;
#pragma unroll
    for (int ct = 0; ct < 8; ++ct) {
      const int col = ct * 16 + m;
#pragma unroll
      for (int rt = 0; rt < RT; ++rt) {
#pragma unroll
        for (int r = 0; r < 4; ++r) {
          const int row = rowbase + rt * 16 + q * 4 + r;
          out[row * DIM + col] = acc[rt][ct][r];
        }
      }
    }
  }
}

// ---------------- prep: fp32 weights -> bf16 in ws (6 x 128x128)
__global__ void prep_kernel(const float* __restrict__ w0, const float* __restrict__ w1,
                            const float* __restrict__ w2, const float* __restrict__ w3,
                            const float* __restrict__ w4, const float* __restrict__ w5,
                            __bf16* __restrict__ dst)
{
  const int idx = blockIdx.x * blockDim.x + threadIdx.x;   // 0..24575
  const int mi  = idx >> 12;                                // matrix id (4096 float4 chunks each)
  const int j   = (idx & 4095) * 4;
  const float* srcs[6] = {w0, w1, w2, w3, w4, w5};
  const float4 v = *(const float4*)(srcs[mi] + j);
  bf16x4 h = { (__bf16)v.x, (__bf16)v.y, (__bf16)v.z, (__bf16)v.w };
  *(bf16x4*)(dst + mi * 16384 + j) = h;
}

// ---------------- max over sequence axis: agg[b,d] = max_i s_out[b,i,d]  (float4)
__global__ __launch_bounds__(1024) void maxpool_kernel(
    const float* __restrict__ sout, float* __restrict__ agg)
{
  __shared__ float4 red[1024];
  const int b = blockIdx.x;
  const int t = threadIdx.x;
  const int c4 = (t & 31) * 4, rg = t >> 5;          // 32 row-groups
  const float* p = sout + (long)b * SEQ * DIM + c4;
  float4 mx = {-INFINITY, -INFINITY, -INFINITY, -INFINITY};
#pragma unroll 4
  for (int i = rg; i < SEQ; i += 32) {
    const float4 v = *(const float4*)(p + (long)i * DIM);
    mx.x = fmaxf(mx.x, v.x); mx.y = fmaxf(mx.y, v.y);
    mx.z = fmaxf(mx.z, v.z); mx.w = fmaxf(mx.w, v.w);
  }
  red[t] = mx;
  __syncthreads();
  if (t < 32) {
    float4 a = red[t];
#pragma unroll
    for (int k = 1; k < 32; ++k) {
      const float4 v = red[t + 32 * k];
      a.x = fmaxf(a.x, v.x); a.y = fmaxf(a.y, v.y);
      a.z = fmaxf(a.z, v.z); a.w = fmaxf(a.w, v.w);
    }
    *(float4*)(agg + b * DIM + c4) = a;
  }
}

extern "C" void kernel_launch(void* const* d_in, const int* in_sizes, int n_in,
                              void* d_out, int out_size, void* d_ws, size_t ws_size,
                              hipStream_t stream)
{
  const float* s     = (const float*)d_in[0];
  const float* c     = (const float*)d_in[1];
  const float* s_w1  = (const float*)d_in[2];
  const float* s_b1  = (const float*)d_in[3];
  const float* s_g1  = (const float*)d_in[4];
  const float* s_be1 = (const float*)d_in[5];
  const float* s_w2  = (const float*)d_in[6];
  const float* s_b2  = (const float*)d_in[7];
  const float* s_g2  = (const float*)d_in[8];
  const float* s_be2 = (const float*)d_in[9];
  const float* s_w3  = (const float*)d_in[10];
  const float* s_b3  = (const float*)d_in[11];
  const float* c_w1  = (const float*)d_in[12];
  const float* c_b1  = (const float*)d_in[13];
  const float* c_g1  = (const float*)d_in[14];
  const float* c_be1 = (const float*)d_in[15];
  const float* c_w2  = (const float*)d_in[16];
  const float* c_b2  = (const float*)d_in[17];
  const float* c_g2  = (const float*)d_in[18];
  const float* c_be2 = (const float*)d_in[19];
  const float* c_w3  = (const float*)d_in[20];
  const float* c_b3  = (const float*)d_in[21];

  float* out   = (float*)d_out;                         // s_out then aggregated
  float* c_out = (float*)d_ws;                          // 32768 floats
  __bf16* wbf  = (__bf16*)((char*)d_ws + (size_t)BATCH * DIM * sizeof(float));

  // 1) weights fp32 -> bf16 (s_w1,s_w2,s_w3,c_w1,c_w2,c_w3)
  prep_kernel<<<96, 256, 0, stream>>>(s_w1, s_w2, s_w3, c_w1, c_w2, c_w3, wbf);

  // 2) c-path MLP -> c_out (ws). One workgroup (BN couples all 256 rows); NW=16 halves
  //    the serial latency chain vs NW=8. Relaxed bound (cap 256) -> no spills.
  mlp_kernel<16, false><<<1, 1024, 0, stream>>>(
      c, (long)DIM,
      wbf + 3 * 16384, wbf + 4 * 16384, wbf + 5 * 16384,
      c_b1, c_g1, c_be1, c_b2, c_g2, c_be2, c_b3,
      nullptr, c_out);

  // 3) s-path MLP per slice, gated by c_out -> s_out
  //    NW=8: 512 thr, RT=2; LDS 71.7KB -> 2 blocks/CU = 16 waves/CU
  mlp_kernel<8, true><<<SEQ, 512, 0, stream>>>(
      s, (long)SEQ * DIM,
      wbf, wbf + 16384, wbf + 2 * 16384,
      s_b1, s_g1, s_be1, s_b2, s_g2, s_be2, s_b3,
      c_out, out);

  // 4) aggregated = max over sequence axis (float4)
  maxpool_kernel<<<BATCH, 1024, 0, stream>>>(out, out + (long)BATCH * SEQ * DIM);
}

// Round 3
// 231.430 us; speedup vs baseline: 1.2169x; 1.2169x over previous
//
#include <hip/hip_runtime.h>
#include <hip/hip_bf16.h>
#include <math.h>

#define BATCH 256
#define SEQ   512
#define DIM   128
#define LDSK  136   // padded LDS row stride in bf16 elems (272 B)
#define LDSF  132   // padded f32 relayout stride (528 B)

typedef __attribute__((ext_vector_type(8))) __bf16  bf16x8;
typedef __attribute__((ext_vector_type(4))) __bf16  bf16x4;
typedef __attribute__((ext_vector_type(4))) float   f32x4;

// ---------------- MFMA layer: acc[RT][8] = X(256xK) @ W^T + bias (full-width bw[8], R0 style)
template<int RT>
__device__ __forceinline__ void matmul_layer(
    const __bf16* __restrict__ Xa, const __bf16* __restrict__ wg,
    const float* bias, f32x4 (&acc)[RT][8], int wave, int m, int q)
{
  const int rowbase = wave * RT * 16;
#pragma unroll
  for (int ct = 0; ct < 8; ++ct) {
    const float b = bias[ct * 16 + m];          // bias staged in LDS
    const f32x4 bv = {b, b, b, b};
#pragma unroll
    for (int rt = 0; rt < RT; ++rt) acc[rt][ct] = bv;
  }
#pragma unroll
  for (int ks = 0; ks < 4; ++ks) {
    const int k0 = ks * 32 + q * 8;
    bf16x8 a[RT], bw[8];
#pragma unroll
    for (int rt = 0; rt < RT; ++rt)
      a[rt] = *(const bf16x8*)(Xa + (rowbase + rt * 16 + m) * LDSK + k0);
#pragma unroll
    for (int ct = 0; ct < 8; ++ct)
      bw[ct] = *(const bf16x8*)(wg + (ct * 16 + m) * DIM + k0);
#pragma unroll
    for (int rt = 0; rt < RT; ++rt)
#pragma unroll
      for (int ct = 0; ct < 8; ++ct)
        acc[rt][ct] = __builtin_amdgcn_mfma_f32_16x16x32_bf16(a[rt], bw[ct], acc[rt][ct], 0, 0, 0);
  }
}

template<int RT>
__device__ __forceinline__ void stats_accum(
    const f32x4 (&acc)[RT][8], float* sumL, float* sqL, int m, int q)
{
#pragma unroll
  for (int ct = 0; ct < 8; ++ct) {
    float s = 0.f, ss = 0.f;
#pragma unroll
    for (int rt = 0; rt < RT; ++rt)
#pragma unroll
      for (int r = 0; r < 4; ++r) { const float v = acc[rt][ct][r]; s += v; ss += v * v; }
    s  += __shfl_xor(s, 16, 64);  s  += __shfl_xor(s, 32, 64);
    ss += __shfl_xor(ss, 16, 64); ss += __shfl_xor(ss, 32, 64);
    if (q == 0) { atomicAdd(&sumL[ct * 16 + m], s); atomicAdd(&sqL[ct * 16 + m], ss); }
  }
}

// fused BN-coef (redundant per thread) + ReLU + store; Xa stripe is wave-private so no
// barrier is needed between this store and the next matmul. g/be come from LDS (prm).
template<int RT>
__device__ __forceinline__ void bn_relu_store(
    const f32x4 (&acc)[RT][8], __bf16* Xa, const float* sumL, const float* sqL,
    const float* g, const float* be, int wave, int m, int q)
{
  const int rowbase = wave * RT * 16;
#pragma unroll
  for (int ct = 0; ct < 8; ++ct) {
    const int n = ct * 16 + m;
    const float mean = sumL[n] * (1.0f / BATCH);
    const float var  = sqL[n]  * (1.0f / BATCH) - mean * mean;
    const float a = g[n] * rsqrtf(var + 1e-5f);
    const float c = be[n] - a * mean;
#pragma unroll
    for (int rt = 0; rt < RT; ++rt)
#pragma unroll
      for (int r = 0; r < 4; ++r) {
        const float y = fmaxf(0.f, a * acc[rt][ct][r] + c);
        const int row = rowbase + rt * 16 + q * 4 + r;
        Xa[row * LDSK + n] = (__bf16)y;
      }
  }
}

// ---------------- fused MLP kernel: one workgroup = one 256x128 batch problem
template<int NW, bool GATE>
__global__ __launch_bounds__(NW * 64, 2)     // cap 256 regs/thread: NO spills (R0-proven)
void mlp_kernel(const float* __restrict__ xin, long xrow_stride,
                const __bf16* __restrict__ w1, const __bf16* __restrict__ w2,
                const __bf16* __restrict__ w3,
                const float* __restrict__ b1, const float* __restrict__ g1, const float* __restrict__ be1,
                const float* __restrict__ b2, const float* __restrict__ g2, const float* __restrict__ be2,
                const float* __restrict__ b3,
                const float* __restrict__ gate,   // c_out [256*128] when GATE
                float* __restrict__ out)          // GATE: s_out base; else c_out (ws)
{
  const int tid  = threadIdx.x;
  constexpr int NT = NW * 64;
  constexpr int RT = 16 / NW;       // row-tiles (of 16) per wave; 256 rows total
  const int wave = tid >> 6, lane = tid & 63;
  const int m = lane & 15, q = lane >> 4;
  const int slice = GATE ? blockIdx.x : 0;
  const float* x0 = GATE ? (xin + (long)slice * DIM) : xin;

  __shared__ __align__(16) char XaRaw[BATCH * LDSK * 2];   // 69632 B; reused as Xf (2x 64x132 f32)
  __bf16* Xa = (__bf16*)XaRaw;
  __shared__ float sum1[DIM], sq1[DIM], sum2[DIM], sq2[DIM];
  __shared__ float prm[7 * DIM];    // b1,g1,be1,b2,g2,be2,b3 staged from global

  for (int t = tid; t < DIM; t += NT) { sum1[t] = 0.f; sq1[t] = 0.f; sum2[t] = 0.f; sq2[t] = 0.f; }
  if (tid < DIM) {
    prm[tid]           = b1[tid];  prm[DIM + tid]     = g1[tid];  prm[2 * DIM + tid] = be1[tid];
    prm[3 * DIM + tid] = b2[tid];  prm[4 * DIM + tid] = g2[tid];  prm[5 * DIM + tid] = be2[tid];
    prm[6 * DIM + tid] = b3[tid];
  }

  // stage X -> LDS bf16 (coalesced: 32 lanes span one 512B row)
  {
    const int rpi = NT / 32;
    const int r0  = tid >> 5;
    const int c4  = (tid & 31) * 4;
#pragma unroll
    for (int it = 0; it < BATCH / rpi; ++it) {
      const int r = it * rpi + r0;
      const float4 v = *(const float4*)(x0 + (long)r * xrow_stride + c4);
      bf16x4 h = { (__bf16)v.x, (__bf16)v.y, (__bf16)v.z, (__bf16)v.w };
      *(bf16x4*)(Xa + r * LDSK + c4) = h;
    }
  }
  __syncthreads();

  f32x4 acc[RT][8];

  // Layer 1: matmul -> stats -> barrier -> fused coefs+ReLU+store (wave-private stripe)
  matmul_layer<RT>(Xa, w1, prm, acc, wave, m, q);
  stats_accum<RT>(acc, sum1, sq1, m, q);
  __syncthreads();
  bn_relu_store<RT>(acc, Xa, sum1, sq1, prm + DIM, prm + 2 * DIM, wave, m, q);

  // Layer 2
  matmul_layer<RT>(Xa, w2, prm + 3 * DIM, acc, wave, m, q);
  stats_accum<RT>(acc, sum2, sq2, m, q);
  __syncthreads();
  bn_relu_store<RT>(acc, Xa, sum2, sq2, prm + 4 * DIM, prm + 5 * DIM, wave, m, q);

  // Layer 3 + epilogue
  matmul_layer<RT>(Xa, w3, prm + 6 * DIM, acc, wave, m, q);

  if constexpr (GATE) {
    // Xa dead. Double-buffered f32 relayout (2 x 64 rows x LDSF = 67584 B <= 69632):
    // one barrier per 64-row chunk; gate loads and stores are float4, full 512B rows.
    float* Xf = (float*)XaRaw;
    const int c4l = (tid & 31) * 4;
    const int r0  = tid >> 5;                 // 0..7 (NW=4)
    __syncthreads();                           // all waves done reading Xa (L3 matmul)
#pragma unroll
    for (int rt = 0; rt < RT; ++rt) {
      float* buf = Xf + (rt & 1) * 64 * LDSF;
#pragma unroll
      for (int ct = 0; ct < 8; ++ct)
#pragma unroll
        for (int r = 0; r < 4; ++r)
          buf[(wave * 16 + q * 4 + r) * LDSF + ct * 16 + m] = acc[rt][ct][r];
      __syncthreads();                         // chunk written; safe: other buffer next
#pragma unroll
      for (int it = 0; it < 8; ++it) {
        const int crow = it * 8 + r0;                           // 0..63
        const int grow = (crow >> 4) * 64 + rt * 16 + (crow & 15);
        float4 y = *(const float4*)(buf + crow * LDSF + c4l);
        const float4 gv = *(const float4*)(gate + grow * DIM + c4l);
        y.x *= gv.x; y.y *= gv.y; y.z *= gv.z; y.w *= gv.w;
        *(float4*)(out + ((long)grow * SEQ + slice) * DIM + c4l) = y;
      }
    }
  } else {
    const int rowbase = wave * RT * 16;
#pragma unroll
    for (int ct = 0; ct < 8; ++ct) {
      const int col = ct * 16 + m;
#pragma unroll
      for (int rt = 0; rt < RT; ++rt) {
#pragma unroll
        for (int r = 0; r < 4; ++r) {
          const int row = rowbase + rt * 16 + q * 4 + r;
          out[row * DIM + col] = acc[rt][ct][r];
        }
      }
    }
  }
}

// ---------------- prep: fp32 weights -> bf16 in ws (6 x 128x128)
__global__ void prep_kernel(const float* __restrict__ w0, const float* __restrict__ w1,
                            const float* __restrict__ w2, const float* __restrict__ w3,
                            const float* __restrict__ w4, const float* __restrict__ w5,
                            __bf16* __restrict__ dst)
{
  const int idx = blockIdx.x * blockDim.x + threadIdx.x;   // 0..24575
  const int mi  = idx >> 12;                                // matrix id (4096 float4 chunks each)
  const int j   = (idx & 4095) * 4;
  const float* srcs[6] = {w0, w1, w2, w3, w4, w5};
  const float4 v = *(const float4*)(srcs[mi] + j);
  bf16x4 h = { (__bf16)v.x, (__bf16)v.y, (__bf16)v.z, (__bf16)v.w };
  *(bf16x4*)(dst + mi * 16384 + j) = h;
}

// ---------------- max over sequence axis: agg[b,d] = max_i s_out[b,i,d]  (float4)
__global__ __launch_bounds__(1024) void maxpool_kernel(
    const float* __restrict__ sout, float* __restrict__ agg)
{
  __shared__ float4 red[1024];
  const int b = blockIdx.x;
  const int t = threadIdx.x;
  const int c4 = (t & 31) * 4, rg = t >> 5;          // 32 row-groups
  const float* p = sout + (long)b * SEQ * DIM + c4;
  float4 mx = {-INFINITY, -INFINITY, -INFINITY, -INFINITY};
#pragma unroll 4
  for (int i = rg; i < SEQ; i += 32) {
    const float4 v = *(const float4*)(p + (long)i * DIM);
    mx.x = fmaxf(mx.x, v.x); mx.y = fmaxf(mx.y, v.y);
    mx.z = fmaxf(mx.z, v.z); mx.w = fmaxf(mx.w, v.w);
  }
  red[t] = mx;
  __syncthreads();
  if (t < 32) {
    float4 a = red[t];
#pragma unroll
    for (int k = 1; k < 32; ++k) {
      const float4 v = red[t + 32 * k];
      a.x = fmaxf(a.x, v.x); a.y = fmaxf(a.y, v.y);
      a.z = fmaxf(a.z, v.z); a.w = fmaxf(a.w, v.w);
    }
    *(float4*)(agg + b * DIM + c4) = a;
  }
}

extern "C" void kernel_launch(void* const* d_in, const int* in_sizes, int n_in,
                              void* d_out, int out_size, void* d_ws, size_t ws_size,
                              hipStream_t stream)
{
  const float* s     = (const float*)d_in[0];
  const float* c     = (const float*)d_in[1];
  const float* s_w1  = (const float*)d_in[2];
  const float* s_b1  = (const float*)d_in[3];
  const float* s_g1  = (const float*)d_in[4];
  const float* s_be1 = (const float*)d_in[5];
  const float* s_w2  = (const float*)d_in[6];
  const float* s_b2  = (const float*)d_in[7];
  const float* s_g2  = (const float*)d_in[8];
  const float* s_be2 = (const float*)d_in[9];
  const float* s_w3  = (const float*)d_in[10];
  const float* s_b3  = (const float*)d_in[11];
  const float* c_w1  = (const float*)d_in[12];
  const float* c_b1  = (const float*)d_in[13];
  const float* c_g1  = (const float*)d_in[14];
  const float* c_be1 = (const float*)d_in[15];
  const float* c_w2  = (const float*)d_in[16];
  const float* c_b2  = (const float*)d_in[17];
  const float* c_g2  = (const float*)d_in[18];
  const float* c_be2 = (const float*)d_in[19];
  const float* c_w3  = (const float*)d_in[20];
  const float* c_b3  = (const float*)d_in[21];

  float* out   = (float*)d_out;                         // s_out then aggregated
  float* c_out = (float*)d_ws;                          // 32768 floats
  __bf16* wbf  = (__bf16*)((char*)d_ws + (size_t)BATCH * DIM * sizeof(float));

  // 1) weights fp32 -> bf16 (s_w1,s_w2,s_w3,c_w1,c_w2,c_w3)
  prep_kernel<<<96, 256, 0, stream>>>(s_w1, s_w2, s_w3, c_w1, c_w2, c_w3, wbf);

  // 2) c-path MLP -> c_out (ws), single workgroup of 8 waves (R0-proven config)
  mlp_kernel<8, false><<<1, 512, 0, stream>>>(
      c, (long)DIM,
      wbf + 3 * 16384, wbf + 4 * 16384, wbf + 5 * 16384,
      c_b1, c_g1, c_be1, c_b2, c_g2, c_be2, c_b3,
      nullptr, c_out);

  // 3) s-path MLP per slice, gated by c_out -> s_out
  //    NW=4, 256 thr, cap-256 regs (no spills), LDS 75.3KB -> 2 blocks/CU
  mlp_kernel<4, true><<<SEQ, 256, 0, stream>>>(
      s, (long)SEQ * DIM,
      wbf, wbf + 16384, wbf + 2 * 16384,
      s_b1, s_g1, s_be1, s_b2, s_g2, s_be2, s_b3,
      c_out, out);

  // 4) aggregated = max over sequence axis (float4)
  maxpool_kernel<<<BATCH, 1024, 0, stream>>>(out, out + (long)BATCH * SEQ * DIM);
}